// Round 2
// baseline (1284.888 us; speedup 1.0000x reference)
//
#include <hip/hip_runtime.h>
#include <hip/hip_bf16.h>

#define BB 8192
#define TT 8
#define DEe 512
#define DRr 1024
#define HH 1024
#define KP 1536    // projection K = 512 + 1024
#define MP 65536   // projection M = B*T

typedef __attribute__((ext_vector_type(8))) __bf16 bf16x8;
typedef __attribute__((ext_vector_type(4))) __bf16 bf16x4;
typedef __attribute__((ext_vector_type(4))) float f32x4;

__device__ __forceinline__ void gld_lds16(const __bf16* g, __bf16* l) {
    __builtin_amdgcn_global_load_lds(
        (const __attribute__((address_space(1))) void*)g,
        (__attribute__((address_space(3))) void*)l, 16, 0, 0);
}

// Convert ent [8192,8,512] f32 and rel [8192,8,1024] f32 into packed bf16
// Ap [65536 x 1536], row r = b*8+t = [ent[b,t,:] | rel[b,t,:]].
__global__ __launch_bounds__(256) void conv_a(const float* __restrict__ ent,
                                              const float* __restrict__ rel,
                                              __bf16* __restrict__ Ap) {
    const size_t NE4 = (size_t)BB * TT * DEe / 4;   // 8388608 float4s in ent
    size_t i = (size_t)blockIdx.x * 256 + threadIdx.x;
    float4 v; size_t dst;
    if (i < NE4) {
        size_t e = i << 2;
        v = *(const float4*)(ent + e);
        dst = (e >> 9) * KP + (e & 511);
    } else {
        size_t e = (i - NE4) << 2;
        v = *(const float4*)(rel + e);
        dst = (e >> 10) * KP + 512 + (e & 1023);
    }
    bf16x4 o = {(__bf16)v.x, (__bf16)v.y, (__bf16)v.z, (__bf16)v.w};
    *(bf16x4*)(Ap + dst) = o;
}

// Pack weights: Bp [1024 x 1536] = [We | Wr] bf16; Bh [1024 x 1024] = Wh bf16.
__global__ void pack_b(const float* __restrict__ We, const float* __restrict__ Wr,
                       const float* __restrict__ Wh, __bf16* __restrict__ Bp,
                       __bf16* __restrict__ Bh) {
    const int n = blockIdx.y;
    const int sec = blockIdx.x;
    const int i = threadIdx.x;
    float4 v; __bf16* dst;
    if (sec == 0) {
        v = *(const float4*)(We + (size_t)n * DEe + i * 4);
        dst = Bp + (size_t)n * KP + i * 4;
    } else if (sec <= 2) {
        int d = (sec - 1) * 512 + i * 4;
        v = *(const float4*)(Wr + (size_t)n * DRr + d);
        dst = Bp + (size_t)n * KP + 512 + d;
    } else {
        int d = (sec - 3) * 512 + i * 4;
        v = *(const float4*)(Wh + (size_t)n * HH + d);
        dst = Bh + (size_t)n * HH + d;
    }
    bf16x4 o = {(__bf16)v.x, (__bf16)v.y, (__bf16)v.z, (__bf16)v.w};
    *(bf16x4*)dst = o;
}

__global__ void bias_k(const float* __restrict__ be, const float* __restrict__ br,
                       const float* __restrict__ bh, float* __restrict__ bias) {
    int i = blockIdx.x * 256 + threadIdx.x;
    if (i < HH) bias[i] = be[i] + br[i] + bh[i];
}

// MODE 0: projection. C[65536,1024] = Ap @ Bp^T -> raw g into out; rows with
//         (m&7)==0 are t=0: finalize relu(g+bias) into out AND h0 (hn).
// MODE 1: recurrence step t. C[8192,1024] = h_{t-1} @ Bh^T;
//         out[b,t,:] = relu(out[b,t,:] + C + bias); hn = bf16(out); t==7 -> need^T.
template <int MODE>
__global__ __launch_bounds__(256) void gemm(
    const __bf16* __restrict__ A, const __bf16* __restrict__ Bw,
    const float* __restrict__ bias, float* __restrict__ out,
    __bf16* __restrict__ hn, float* __restrict__ need, int t) {
    constexpr int K = (MODE == 0) ? KP : HH;
    __shared__ __bf16 sA[128 * 32];
    __shared__ __bf16 sB[128 * 32];
    __shared__ float sBias[128];

    const int tid  = threadIdx.x;
    const int lane = tid & 63;
    const int w    = tid >> 6;
    const int tileM = blockIdx.y * 128;
    const int tileN = blockIdx.x * 128;

    if (tid < 128) sBias[tid] = bias[tileN + tid];

    // staging: instr j of wave w fills LDS bytes (w*2+j)*1024 + lane*16
    const int r0 = (w * 2 + 0) * 16 + (lane >> 2);
    const int r1 = (w * 2 + 1) * 16 + (lane >> 2);
    const int cc = (lane & 3) * 8;
    const __bf16* gA0 = A + (size_t)(tileM + r0) * K + cc;
    const __bf16* gA1 = A + (size_t)(tileM + r1) * K + cc;
    const __bf16* gB0 = Bw + (size_t)(tileN + r0) * K + cc;
    const __bf16* gB1 = Bw + (size_t)(tileN + r1) * K + cc;
    __bf16* lA0 = sA + (w * 2 + 0) * 512;
    __bf16* lA1 = sA + (w * 2 + 1) * 512;
    __bf16* lB0 = sB + (w * 2 + 0) * 512;
    __bf16* lB1 = sB + (w * 2 + 1) * 512;

    const int wm = (w >> 1) * 64, wn = (w & 1) * 64;
    const int fm = lane & 15, fq = lane >> 4;

    f32x4 acc[4][4];
#pragma unroll
    for (int i = 0; i < 4; i++)
#pragma unroll
        for (int j = 0; j < 4; j++) acc[i][j] = {0.f, 0.f, 0.f, 0.f};

    for (int k0 = 0; k0 < K; k0 += 32) {
        gld_lds16(gA0 + k0, lA0);
        gld_lds16(gA1 + k0, lA1);
        gld_lds16(gB0 + k0, lB0);
        gld_lds16(gB1 + k0, lB1);
        __syncthreads();
        bf16x8 af[4], bf[4];
#pragma unroll
        for (int mf = 0; mf < 4; mf++)
            af[mf] = *(const bf16x8*)&sA[(wm + mf * 16 + fm) * 32 + fq * 8];
#pragma unroll
        for (int nf = 0; nf < 4; nf++)
            bf[nf] = *(const bf16x8*)&sB[(wn + nf * 16 + fm) * 32 + fq * 8];
#pragma unroll
        for (int mf = 0; mf < 4; mf++)
#pragma unroll
            for (int nf = 0; nf < 4; nf++)
                acc[mf][nf] = __builtin_amdgcn_mfma_f32_16x16x32_bf16(
                    af[mf], bf[nf], acc[mf][nf], 0, 0, 0);
        __syncthreads();
    }

    // C/D layout: col = lane&15, row = (lane>>4)*4 + reg
#pragma unroll
    for (int mf = 0; mf < 4; mf++) {
#pragma unroll
        for (int nf = 0; nf < 4; nf++) {
            f32x4 v = acc[mf][nf];
            const int nl = wn + nf * 16 + fm;
            const int n  = tileN + nl;
            const int m0 = tileM + wm + mf * 16 + fq * 4;
            if (MODE == 0) {
#pragma unroll
                for (int r = 0; r < 4; r++) {
                    int row = m0 + r;          // global row in [0, 65536)
                    float x = v[r];
                    if ((row & 7) == 0) {      // t == 0: finalize
                        x += sBias[nl];
                        x = x > 0.f ? x : 0.f;
                        hn[(size_t)(row >> 3) * HH + n] = (__bf16)x;
                    }
                    out[(size_t)row * HH + n] = x;
                }
            } else {
                float hv[4];
#pragma unroll
                for (int r = 0; r < 4; r++) {
                    int m = m0 + r;            // batch row in [0, 8192)
                    size_t gidx = ((size_t)m * TT + t) * HH + n;
                    float x = out[gidx] + v[r] + sBias[nl];
                    x = x > 0.f ? x : 0.f;
                    hv[r] = x;
                    out[gidx] = x;
                    hn[(size_t)m * HH + n] = (__bf16)x;
                }
                if (need) {
                    f32x4 nv = {hv[0], hv[1], hv[2], hv[3]};
                    *(f32x4*)&need[(size_t)n * BB + m0] = nv;
                }
            }
        }
    }
}

extern "C" void kernel_launch(void* const* d_in, const int* in_sizes, int n_in,
                              void* d_out, int out_size, void* d_ws, size_t ws_size,
                              hipStream_t stream) {
    const float* ent = (const float*)d_in[0];
    const float* rel = (const float*)d_in[1];
    const float* We  = (const float*)d_in[2];
    const float* be  = (const float*)d_in[3];
    const float* Wr  = (const float*)d_in[4];
    const float* br  = (const float*)d_in[5];
    const float* Wh  = (const float*)d_in[6];
    const float* bh  = (const float*)d_in[7];

    float* out  = (float*)d_out;
    float* need = out + (size_t)BB * TT * HH;   // [H, B]

    char* ws = (char*)d_ws;
    size_t off = 0;
    __bf16* Ap = (__bf16*)(ws + off); off += (size_t)MP * KP * 2;   // 201.3 MB
    __bf16* Bp = (__bf16*)(ws + off); off += (size_t)HH * KP * 2;   // 3.1 MB
    __bf16* Bh = (__bf16*)(ws + off); off += (size_t)HH * HH * 2;   // 2.1 MB
    float*  bias = (float*)(ws + off); off += HH * 4;
    __bf16* hb0 = (__bf16*)(ws + off); off += (size_t)BB * HH * 2;  // 16.8 MB
    __bf16* hb1 = (__bf16*)(ws + off);
    __bf16* hb[2] = {hb0, hb1};

    conv_a<<<98304, 256, 0, stream>>>(ent, rel, Ap);
    pack_b<<<dim3(5, 1024), 128, 0, stream>>>(We, Wr, Wh, Bp, Bh);
    bias_k<<<4, 256, 0, stream>>>(be, br, bh, bias);

    // projection + fused t=0: grid (N tiles = 8, M tiles = 512)
    gemm<0><<<dim3(8, 512), 256, 0, stream>>>(Ap, Bp, bias, out, hb0, nullptr, 0);

    // recurrence t = 1..7
    for (int t = 1; t < TT; t++) {
        gemm<1><<<dim3(8, 64), 256, 0, stream>>>(
            hb[(t - 1) & 1], Bh, bias, out, hb[t & 1],
            (t == 7) ? need : nullptr, t);
    }
}